// Round 11
// baseline (157.665 us; speedup 1.0000x reference)
//
#include <hip/hip_runtime.h>
#include <hip/hip_bf16.h>
#include <math.h>

#define ALPHA 0.2f
#define ACVT 0.01f

typedef __attribute__((ext_vector_type(8))) __bf16 bf16x8;
typedef __attribute__((ext_vector_type(4))) __bf16 bf16x4;
typedef __attribute__((ext_vector_type(4))) float f32x4;

__device__ __forceinline__ bf16x8 cvt8(const float* p) {
    float4 v0 = *(const float4*)p;
    float4 v1 = *(const float4*)(p + 4);
    bf16x8 o;
    o[0] = (__bf16)v0.x; o[1] = (__bf16)v0.y; o[2] = (__bf16)v0.z; o[3] = (__bf16)v0.w;
    o[4] = (__bf16)v1.x; o[5] = (__bf16)v1.y; o[6] = (__bf16)v1.z; o[7] = (__bf16)v1.w;
    return o;
}

// ============================================================================
// GEMM1 (round-6 best): HT[(b*8+h)*64+d][n] = sum_f X[n][f]*Wt[h*64+d][f]
// BM=BN=128, KC=64, grid 512 XCD-chunked. HT store via padded LDS transpose.
// Fused e1/e2.
// ============================================================================
__global__ __launch_bounds__(256) void gemm1_f(
    const float* __restrict__ X, const float* __restrict__ Wt,
    __bf16* __restrict__ HT,
    const float* __restrict__ a1, const float* __restrict__ a2,
    float* __restrict__ E1, float* __restrict__ E2) {
    __shared__ char As[128 * 128];
    __shared__ char Bs[128 * 128];
    __shared__ char Tt[128 * 264];
    const int tid = threadIdx.x;
    const int w = tid >> 6, lane = tid & 63;
    const int wm = w >> 1, wn = w & 1;
    const int r = lane & 15, g = lane >> 4;
    const int L = blockIdx.x;
    const int W = (L & 7) * 64 + (L >> 3);
    const int m_tile = W >> 2, n_tile = W & 3;
    const int m0 = m_tile * 128;
    const int n0 = n_tile * 128;

    f32x4 acc[4][4];
#pragma unroll
    for (int mt = 0; mt < 4; ++mt)
#pragma unroll
        for (int nt = 0; nt < 4; ++nt) {
            acc[mt][nt][0] = 0.f; acc[mt][nt][1] = 0.f;
            acc[mt][nt][2] = 0.f; acc[mt][nt][3] = 0.f;
        }

    const int sr = tid >> 3;
    const int c8 = (tid & 7) * 8;

    for (int k0 = 0; k0 < 256; k0 += 64) {
        __syncthreads();
#pragma unroll
        for (int i = 0; i < 4; ++i) {
            int row = sr + i * 32;
            bf16x8 va = cvt8(X + (size_t)(m0 + row) * 256 + k0 + c8);
            *(bf16x8*)(As + row * 128 + ((c8 * 2) ^ ((row & 7) << 4))) = va;
            bf16x8 vb = cvt8(Wt + (size_t)(n0 + row) * 256 + k0 + c8);
            *(bf16x8*)(Bs + row * 128 + ((c8 * 2) ^ ((row & 7) << 4))) = vb;
        }
        __syncthreads();
#pragma unroll
        for (int kk = 0; kk < 64; kk += 32) {
            bf16x8 af[4], bfv[4];
#pragma unroll
            for (int mt = 0; mt < 4; ++mt) {
                int row = wm * 64 + mt * 16 + r;
                af[mt] = *(const bf16x8*)(As + row * 128 +
                                          (((kk + g * 8) * 2) ^ ((row & 7) << 4)));
            }
#pragma unroll
            for (int nt = 0; nt < 4; ++nt) {
                int row = wn * 64 + nt * 16 + r;
                bfv[nt] = *(const bf16x8*)(Bs + row * 128 +
                                           (((kk + g * 8) * 2) ^ ((row & 7) << 4)));
            }
#pragma unroll
            for (int mt = 0; mt < 4; ++mt)
#pragma unroll
                for (int nt = 0; nt < 4; ++nt)
                    acc[mt][nt] = __builtin_amdgcn_mfma_f32_16x16x32_bf16(
                        af[mt], bfv[nt], acc[mt][nt], 0, 0, 0);
        }
    }

#pragma unroll
    for (int mt = 0; mt < 4; ++mt) {
        int node = wm * 64 + mt * 16 + g * 4;
#pragma unroll
        for (int nt = 0; nt < 4; ++nt) {
            int d_blk = wn * 64 + nt * 16 + r;
            bf16x4 pv;
#pragma unroll
            for (int reg = 0; reg < 4; ++reg) pv[reg] = (__bf16)acc[mt][nt][reg];
            *(bf16x4*)(Tt + d_blk * 264 + node * 2) = pv;
        }
    }
    __syncthreads();
    {
        const int b = m0 >> 9, nn = m0 & 511;
        const int h0 = n_tile * 2;
#pragma unroll
        for (int i = 0; i < 8; ++i) {
            int d_row = (tid >> 4) + i * 16;
            int hrow = (b * 8 + h0 + (d_row >> 6)) * 64 + (d_row & 63);
            bf16x8 v = *(const bf16x8*)(Tt + d_row * 264 + (tid & 15) * 16);
            *(bf16x8*)(HT + (size_t)hrow * 512 + nn + (tid & 15) * 8) = v;
        }
    }
    const int h = n_tile * 2 + wn;
    float w1[4], w2[4];
#pragma unroll
    for (int nt = 0; nt < 4; ++nt) {
        w1[nt] = a1[h * 64 + nt * 16 + r];
        w2[nt] = a2[h * 64 + nt * 16 + r];
    }
#pragma unroll
    for (int mt = 0; mt < 4; ++mt)
#pragma unroll
        for (int reg = 0; reg < 4; ++reg) {
            float s1 = 0.f, s2 = 0.f;
#pragma unroll
            for (int nt = 0; nt < 4; ++nt) {
                s1 += acc[mt][nt][reg] * w1[nt];
                s2 += acc[mt][nt][reg] * w2[nt];
            }
#pragma unroll
            for (int off = 1; off <= 8; off <<= 1) {
                s1 += __shfl_xor(s1, off, 64);
                s2 += __shfl_xor(s2, off, 64);
            }
            if (r == 0) {
                int m = m0 + wm * 64 + mt * 16 + g * 4 + reg;
                int b = m >> 9, n = m & 511;
                E1[(size_t)(b * 8 + h) * 512 + n] = s1;
                E2[(size_t)(b * 8 + h) * 512 + n] = s2;
            }
        }
}

// ============================================================================
// attn: per (b,h,quarter). Ping-pong double-buffered H^T staging; ONE barrier
// per chunk. Epilogue additionally computes per-head f1/f2 partials:
// f1 += OL_row . (Wo^T a1o)|head-slice  (ã slice computed cooperatively).
// grid 1024, 256 thr.
// ============================================================================
__global__ __launch_bounds__(256) void attn_s(
    const __bf16* __restrict__ HT, const float* __restrict__ E1,
    const float* __restrict__ E2, const float* __restrict__ Wo,
    const float* __restrict__ a1o, const float* __restrict__ a2o,
    __bf16* __restrict__ OL, float* __restrict__ F1P, float* __restrict__ F2P) {
    __shared__ char Hc0[4096];
    __shared__ char Hc1[4096];
    __shared__ float e1s[512];
    __shared__ float redm[256];
    __shared__ float zrow[4][32];
    __shared__ float e1maxS;
    __shared__ float atp[2][4][64];
    __shared__ float at1[64], at2[64];

    const int bid = blockIdx.x;
    const int bh = bid >> 2, qq = bid & 3;
    const int b = bh >> 3, h = bh & 7;
    const int tid = threadIdx.x;
    const int w = tid >> 6, lane = tid & 63;
    const int r = lane & 15, g = lane >> 4;

    // ---- ã slice partials: at[d] = sum_c Wo[c][h*64+d] * a(1/2)o[c] ----
    {
        const int d = tid & 63, part = tid >> 6;
        const float* wop = Wo + (size_t)(part * 32) * 512 + h * 64 + d;
        float p1 = 0.f, p2 = 0.f;
#pragma unroll 8
        for (int c = 0; c < 32; ++c) {
            float wv = wop[(size_t)c * 512];
            p1 += wv * a1o[part * 32 + c];
            p2 += wv * a2o[part * 32 + c];
        }
        atp[0][part][d] = p1;
        atp[1][part][d] = p2;
    }
    for (int i = tid; i < 512; i += 256) e1s[i] = E1[(size_t)bh * 512 + i];
    __syncthreads();
    redm[tid] = fmaxf(e1s[tid], e1s[tid + 256]);
    if (tid < 64)
        at1[tid] = atp[0][0][tid] + atp[0][1][tid] + atp[0][2][tid] + atp[0][3][tid];
    else if (tid < 128) {
        int d = tid - 64;
        at2[d] = atp[1][0][d] + atp[1][1][d] + atp[1][2][d] + atp[1][3][d];
    }
    __syncthreads();
    if (tid < 64) {
        float m = fmaxf(fmaxf(redm[tid], redm[tid + 64]),
                        fmaxf(redm[tid + 128], redm[tid + 192]));
#pragma unroll
        for (int off = 32; off >= 1; off >>= 1) m = fmaxf(m, __shfl_xor(m, off, 64));
        if (tid == 0) e1maxS = m;
    }
    __syncthreads();
    const float e1max = e1maxS;

    float ee2[2], mm[2];
    const float* e2g = E2 + (size_t)bh * 512 + qq * 128 + w * 32;
#pragma unroll
    for (int mt = 0; mt < 2; ++mt) {
        float v = e2g[mt * 16 + r];
        ee2[mt] = v;
        float s = e1max + v;
        mm[mt] = fmaxf(s, ALPHA * s);
    }

    f32x4 acc[2][4];
#pragma unroll
    for (int mt = 0; mt < 2; ++mt)
#pragma unroll
        for (int nt = 0; nt < 4; ++nt) {
            acc[mt][nt][0] = 0.f; acc[mt][nt][1] = 0.f;
            acc[mt][nt][2] = 0.f; acc[mt][nt][3] = 0.f;
        }
    float zac[2] = {0.f, 0.f};

    const int d_s = tid >> 2, kq = tid & 3;
    const __bf16* hsrc = HT + (size_t)(bh * 64 + d_s) * 512 + kq * 8;
    const int lwo = d_s * 64 + ((kq * 16) ^ ((d_s & 3) << 4));
    char* cur = Hc0;
    char* nxt = Hc1;
    *(bf16x8*)(cur + lwo) = *(const bf16x8*)hsrc;
    __syncthreads();

    for (int c = 0; c < 16; ++c) {
        bf16x8 stg;
        if (c < 15) stg = *(const bf16x8*)(hsrc + (c + 1) * 32);  // issue early

        const float* ep = e1s + c * 32 + g * 8;
        float4 ea = *(const float4*)(ep);
        float4 eb = *(const float4*)(ep + 4);
        float e1c[8] = {ea.x, ea.y, ea.z, ea.w, eb.x, eb.y, eb.z, eb.w};

        bf16x8 bfr[4];
#pragma unroll
        for (int nt = 0; nt < 4; ++nt) {
            int d = nt * 16 + r;
            bfr[nt] = *(const bf16x8*)(cur + d * 64 + ((g * 16) ^ ((d & 3) << 4)));
        }
#pragma unroll
        for (int mt = 0; mt < 2; ++mt) {
            bf16x8 af;
            float zp = 0.f;
#pragma unroll
            for (int q = 0; q < 8; ++q) {
                float s = e1c[q] + ee2[mt];
                s = fmaxf(s, ALPHA * s);
                float p = __expf(s - mm[mt]);
                zp += p;
                af[q] = (__bf16)p;
            }
            zac[mt] += zp;
#pragma unroll
            for (int nt = 0; nt < 4; ++nt)
                acc[mt][nt] =
                    __builtin_amdgcn_mfma_f32_16x16x32_bf16(af, bfr[nt], acc[mt][nt], 0, 0, 0);
        }

        if (c < 15) *(bf16x8*)(nxt + lwo) = stg;  // write to idle buffer
        __syncthreads();                          // one barrier per chunk
        char* t = cur; cur = nxt; nxt = t;
    }

#pragma unroll
    for (int mt = 0; mt < 2; ++mt) {
        float z = zac[mt];
        z += __shfl_xor(z, 16, 64);
        z += __shfl_xor(z, 32, 64);
        if (g == 0) zrow[w][mt * 16 + r] = 1.f / z;
    }

    // ---- epilogue: OL store + fused f1/f2 per-head partials ----
    float aa1[4], aa2[4];
#pragma unroll
    for (int nt = 0; nt < 4; ++nt) {
        aa1[nt] = at1[nt * 16 + r];
        aa2[nt] = at2[nt * 16 + r];
    }
    __bf16* ob = OL + ((size_t)b * 512 + qq * 128 + w * 32) * 512 + h * 64;
#pragma unroll
    for (int mt = 0; mt < 2; ++mt) {
#pragma unroll
        for (int reg = 0; reg < 4; ++reg) {
            int row = mt * 16 + g * 4 + reg;
            float zi = zrow[w][row];
            float s1 = 0.f, s2 = 0.f;
#pragma unroll
            for (int nt = 0; nt < 4; ++nt) {
                float v = acc[mt][nt][reg] * zi;
                v = fmaxf(v, ACVT * v);  // leaky 0.01 fused
                ob[(size_t)row * 512 + nt * 16 + r] = (__bf16)v;
                s1 += v * aa1[nt];
                s2 += v * aa2[nt];
            }
#pragma unroll
            for (int off = 1; off <= 8; off <<= 1) {
                s1 += __shfl_xor(s1, off, 64);
                s2 += __shfl_xor(s2, off, 64);
            }
            if (r == 0) {
                int j = qq * 128 + w * 32 + row;
                F1P[(size_t)h * 16384 + b * 512 + j] = s1;
                F2P[(size_t)h * 16384 + b * 512 + j] = s2;
            }
        }
    }
}

// ============================================================================
// zw: per (b, jc): partial w[k] = sum_{j in chunk} softmax_k(leaky(f1+f2))[j,k]
// f1/f2 assembled from 8 per-head partials.
// ============================================================================
__global__ __launch_bounds__(256) void zw_k(const float* __restrict__ F1P,
                                            const float* __restrict__ F2P,
                                            float* __restrict__ WP) {
    __shared__ float f1s[512], f2s[512];
    __shared__ float wpart[4][512];
    __shared__ float redm[256];
    const int b = blockIdx.x >> 4, jc = blockIdx.x & 15;
    const int tid = threadIdx.x;
    const int w = tid >> 6, lane = tid & 63;

    for (int i = tid; i < 512; i += 256) {
        float s1 = 0.f, s2 = 0.f;
#pragma unroll
        for (int hh = 0; hh < 8; ++hh) {
            s1 += F1P[(size_t)hh * 16384 + b * 512 + i];
            s2 += F2P[(size_t)hh * 16384 + b * 512 + i];
        }
        f1s[i] = s1;
        f2s[i] = s2;
    }
#pragma unroll
    for (int i = 0; i < 8; ++i) wpart[w][lane + 64 * i] = 0.f;
    __syncthreads();
    redm[tid] = fmaxf(f1s[tid], f1s[tid + 256]);
    __syncthreads();
    if (tid < 64) {
        float m = fmaxf(fmaxf(redm[tid], redm[tid + 64]), fmaxf(redm[tid + 128], redm[tid + 192]));
#pragma unroll
        for (int off = 32; off >= 1; off >>= 1) m = fmaxf(m, __shfl_xor(m, off, 64));
        if (tid == 0) redm[0] = m;
    }
    __syncthreads();
    const float f1m = redm[0];

    for (int jj = 0; jj < 8; ++jj) {
        int j = jc * 32 + w * 8 + jj;
        float f2j = f2s[j];
        float sj = f1m + f2j;
        float mj = fmaxf(sj, ALPHA * sj);
        float pv[8];
        float z = 0.f;
#pragma unroll
        for (int i = 0; i < 8; ++i) {
            float s = f1s[lane + 64 * i] + f2j;
            s = fmaxf(s, ALPHA * s);
            float p = __expf(s - mj);
            pv[i] = p;
            z += p;
        }
#pragma unroll
        for (int off = 32; off >= 1; off >>= 1) z += __shfl_xor(z, off, 64);
        float inv = 1.f / z;
#pragma unroll
        for (int i = 0; i < 8; ++i) wpart[w][lane + 64 * i] += pv[i] * inv;
    }
    __syncthreads();
    for (int i = tid; i < 512; i += 256)
        WP[(size_t)(b * 16 + jc) * 512 + i] =
            wpart[0][i] + wpart[1][i] + wpart[2][i] + wpart[3][i];
}

// ============================================================================
// ufinal: per b: w = sum WP; u = (w/512).OL (512-dim); v = u.Wo^T (128);
// out = normalize(v @ Wl^T + bl). 512 thr, grid 32.
// ============================================================================
__global__ __launch_bounds__(512) void ufinal_k(const float* __restrict__ WP,
                                                const __bf16* __restrict__ OL,
                                                const float* __restrict__ Wo,
                                                const float* __restrict__ Wl,
                                                const float* __restrict__ bl,
                                                float* __restrict__ out) {
    __shared__ float wsL[512];
    __shared__ float us[512];
    __shared__ float part[4][128];
    __shared__ float vfull[128];
    __shared__ float fo_s[128];
    __shared__ float r0;
    const int b = blockIdx.x, tid = threadIdx.x;
    {
        float s = 0.f;
#pragma unroll
        for (int jc = 0; jc < 16; ++jc) s += WP[(size_t)(b * 16 + jc) * 512 + tid];
        wsL[tid] = s;
    }
    __syncthreads();
    {   // u[d] = (1/512) * sum_k w[k]*OL[b,k,d]
        const __bf16* olp = OL + (size_t)b * 512 * 512 + tid;
        float acc = 0.f;
#pragma unroll 8
        for (int k = 0; k < 512; ++k) acc += wsL[k] * (float)olp[(size_t)k * 512];
        us[tid] = acc * (1.f / 512.f);
    }
    __syncthreads();
    {   // v[c] = sum_d u[d]*Wo[c][d], k-split 4 ways
        const int c = tid & 127, q = tid >> 7;
        const float* wop = Wo + (size_t)c * 512 + q * 128;
        float pp = 0.f;
#pragma unroll 8
        for (int i = 0; i < 128; ++i) pp += us[q * 128 + i] * wop[i];
        part[q][c] = pp;
    }
    __syncthreads();
    if (tid < 128)
        vfull[tid] = part[0][tid] + part[1][tid] + part[2][tid] + part[3][tid];
    __syncthreads();
    if (tid < 128) {
        float fo = bl[tid];
        const float* wl = Wl + (size_t)tid * 128;
#pragma unroll 4
        for (int d = 0; d < 128; d += 4)
            fo += vfull[d] * wl[d] + vfull[d + 1] * wl[d + 1] +
                  vfull[d + 2] * wl[d + 2] + vfull[d + 3] * wl[d + 3];
        fo_s[tid] = fo;
    }
    __syncthreads();
    if (tid < 64) {
        float s = fo_s[tid] * fo_s[tid] + fo_s[tid + 64] * fo_s[tid + 64];
#pragma unroll
        for (int off = 32; off >= 1; off >>= 1) s += __shfl_xor(s, off, 64);
        if (tid == 0) r0 = s;
    }
    __syncthreads();
    float inv = 1.f / fmaxf(sqrtf(r0), 1e-12f);
    if (tid < 128) out[(size_t)b * 128 + tid] = fo_s[tid] * inv;
}

extern "C" void kernel_launch(void* const* d_in, const int* in_sizes, int n_in,
                              void* d_out, int out_size, void* d_ws, size_t ws_size,
                              hipStream_t stream) {
    const float* X = (const float*)d_in[0];
    const float* Wt = (const float*)d_in[1];
    const float* a1 = (const float*)d_in[2];
    const float* a2 = (const float*)d_in[3];
    const float* Wo = (const float*)d_in[4];
    const float* a1o = (const float*)d_in[5];
    const float* a2o = (const float*)d_in[6];
    const float* Wl = (const float*)d_in[7];
    const float* bl = (const float*)d_in[8];
    float* out = (float*)d_out;

    char* p = (char*)d_ws;
    __bf16* HT = (__bf16*)p;  p += (size_t)8388608 * 2;   // 16 MB
    __bf16* OL = (__bf16*)p;  p += (size_t)8388608 * 2;   // 16 MB
    float* E1 = (float*)p;    p += (size_t)131072 * 4;
    float* E2 = (float*)p;    p += (size_t)131072 * 4;
    float* F1P = (float*)p;   p += (size_t)8 * 16384 * 4; // 512 KB
    float* F2P = (float*)p;   p += (size_t)8 * 16384 * 4; // 512 KB
    float* WP = (float*)p;    p += (size_t)262144 * 4;    // 1 MB

    gemm1_f<<<512, 256, 0, stream>>>(X, Wt, HT, a1, a2, E1, E2);
    attn_s<<<1024, 256, 0, stream>>>(HT, E1, E2, Wo, a1o, a2o, OL, F1P, F2P);
    zw_k<<<512, 256, 0, stream>>>(F1P, F2P, WP);
    ufinal_k<<<32, 512, 0, stream>>>(WP, OL, Wo, Wl, bl, out);
}

// Round 12
// 142.056 us; speedup vs baseline: 1.1099x; 1.1099x over previous
//
#include <hip/hip_runtime.h>
#include <hip/hip_bf16.h>
#include <math.h>

#define ALPHA 0.2f
#define ACVT 0.01f

typedef __attribute__((ext_vector_type(8))) __bf16 bf16x8;
typedef __attribute__((ext_vector_type(4))) __bf16 bf16x4;
typedef __attribute__((ext_vector_type(4))) float f32x4;

__device__ __forceinline__ bf16x8 cvt8(const float* p) {
    float4 v0 = *(const float4*)p;
    float4 v1 = *(const float4*)(p + 4);
    bf16x8 o;
    o[0] = (__bf16)v0.x; o[1] = (__bf16)v0.y; o[2] = (__bf16)v0.z; o[3] = (__bf16)v0.w;
    o[4] = (__bf16)v1.x; o[5] = (__bf16)v1.y; o[6] = (__bf16)v1.z; o[7] = (__bf16)v1.w;
    return o;
}

// ============================================================================
// GEMM1: HT[(b*8+h)*64+d][n] = sum_f X[n][f]*Wt[h*64+d][f]  (bf16 out)
// BM=BN=128, KC=64, grid 512 XCD-chunked. HT store via padded LDS transpose.
// Fused e1/e2.
// ============================================================================
__global__ __launch_bounds__(256) void gemm1_f(
    const float* __restrict__ X, const float* __restrict__ Wt,
    __bf16* __restrict__ HT,
    const float* __restrict__ a1, const float* __restrict__ a2,
    float* __restrict__ E1, float* __restrict__ E2) {
    __shared__ char As[128 * 128];
    __shared__ char Bs[128 * 128];
    __shared__ char Tt[128 * 264];
    const int tid = threadIdx.x;
    const int w = tid >> 6, lane = tid & 63;
    const int wm = w >> 1, wn = w & 1;
    const int r = lane & 15, g = lane >> 4;
    const int L = blockIdx.x;
    const int W = (L & 7) * 64 + (L >> 3);
    const int m_tile = W >> 2, n_tile = W & 3;
    const int m0 = m_tile * 128;
    const int n0 = n_tile * 128;

    f32x4 acc[4][4];
#pragma unroll
    for (int mt = 0; mt < 4; ++mt)
#pragma unroll
        for (int nt = 0; nt < 4; ++nt) {
            acc[mt][nt][0] = 0.f; acc[mt][nt][1] = 0.f;
            acc[mt][nt][2] = 0.f; acc[mt][nt][3] = 0.f;
        }

    const int sr = tid >> 3;
    const int c8 = (tid & 7) * 8;

    for (int k0 = 0; k0 < 256; k0 += 64) {
        __syncthreads();
#pragma unroll
        for (int i = 0; i < 4; ++i) {
            int row = sr + i * 32;
            bf16x8 va = cvt8(X + (size_t)(m0 + row) * 256 + k0 + c8);
            *(bf16x8*)(As + row * 128 + ((c8 * 2) ^ ((row & 7) << 4))) = va;
            bf16x8 vb = cvt8(Wt + (size_t)(n0 + row) * 256 + k0 + c8);
            *(bf16x8*)(Bs + row * 128 + ((c8 * 2) ^ ((row & 7) << 4))) = vb;
        }
        __syncthreads();
#pragma unroll
        for (int kk = 0; kk < 64; kk += 32) {
            bf16x8 af[4], bfv[4];
#pragma unroll
            for (int mt = 0; mt < 4; ++mt) {
                int row = wm * 64 + mt * 16 + r;
                af[mt] = *(const bf16x8*)(As + row * 128 +
                                          (((kk + g * 8) * 2) ^ ((row & 7) << 4)));
            }
#pragma unroll
            for (int nt = 0; nt < 4; ++nt) {
                int row = wn * 64 + nt * 16 + r;
                bfv[nt] = *(const bf16x8*)(Bs + row * 128 +
                                           (((kk + g * 8) * 2) ^ ((row & 7) << 4)));
            }
#pragma unroll
            for (int mt = 0; mt < 4; ++mt)
#pragma unroll
                for (int nt = 0; nt < 4; ++nt)
                    acc[mt][nt] = __builtin_amdgcn_mfma_f32_16x16x32_bf16(
                        af[mt], bfv[nt], acc[mt][nt], 0, 0, 0);
        }
    }

#pragma unroll
    for (int mt = 0; mt < 4; ++mt) {
        int node = wm * 64 + mt * 16 + g * 4;
#pragma unroll
        for (int nt = 0; nt < 4; ++nt) {
            int d_blk = wn * 64 + nt * 16 + r;
            bf16x4 pv;
#pragma unroll
            for (int reg = 0; reg < 4; ++reg) pv[reg] = (__bf16)acc[mt][nt][reg];
            *(bf16x4*)(Tt + d_blk * 264 + node * 2) = pv;
        }
    }
    __syncthreads();
    {
        const int b = m0 >> 9, nn = m0 & 511;
        const int h0 = n_tile * 2;
#pragma unroll
        for (int i = 0; i < 8; ++i) {
            int d_row = (tid >> 4) + i * 16;
            int hrow = (b * 8 + h0 + (d_row >> 6)) * 64 + (d_row & 63);
            bf16x8 v = *(const bf16x8*)(Tt + d_row * 264 + (tid & 15) * 16);
            *(bf16x8*)(HT + (size_t)hrow * 512 + nn + (tid & 15) * 8) = v;
        }
    }
    const int h = n_tile * 2 + wn;
    float w1[4], w2[4];
#pragma unroll
    for (int nt = 0; nt < 4; ++nt) {
        w1[nt] = a1[h * 64 + nt * 16 + r];
        w2[nt] = a2[h * 64 + nt * 16 + r];
    }
#pragma unroll
    for (int mt = 0; mt < 4; ++mt)
#pragma unroll
        for (int reg = 0; reg < 4; ++reg) {
            float s1 = 0.f, s2 = 0.f;
#pragma unroll
            for (int nt = 0; nt < 4; ++nt) {
                s1 += acc[mt][nt][reg] * w1[nt];
                s2 += acc[mt][nt][reg] * w2[nt];
            }
#pragma unroll
            for (int off = 1; off <= 8; off <<= 1) {
                s1 += __shfl_xor(s1, off, 64);
                s2 += __shfl_xor(s2, off, 64);
            }
            if (r == 0) {
                int m = m0 + wm * 64 + mt * 16 + g * 4 + reg;
                int b = m >> 9, n = m & 511;
                E1[(size_t)(b * 8 + h) * 512 + n] = s1;
                E2[(size_t)(b * 8 + h) * 512 + n] = s2;
            }
        }
}

// ============================================================================
// attn: per (b,h,quarter). Ping-pong double-buffered H^T staging, one barrier
// per chunk (R10 best). grid 1024, 256 thr.
// ============================================================================
__global__ __launch_bounds__(256) void attn_s(const __bf16* __restrict__ HT,
                                              const float* __restrict__ E1,
                                              const float* __restrict__ E2,
                                              __bf16* __restrict__ OL) {
    __shared__ char Hc0[4096];
    __shared__ char Hc1[4096];
    __shared__ float e1s[512];
    __shared__ float redm[256];
    __shared__ float zrow[4][32];
    __shared__ float e1maxS;

    const int bid = blockIdx.x;
    const int bh = bid >> 2, qq = bid & 3;
    const int b = bh >> 3, h = bh & 7;
    const int tid = threadIdx.x;
    const int w = tid >> 6, lane = tid & 63;
    const int r = lane & 15, g = lane >> 4;

    for (int i = tid; i < 512; i += 256) e1s[i] = E1[(size_t)bh * 512 + i];
    __syncthreads();
    redm[tid] = fmaxf(e1s[tid], e1s[tid + 256]);
    __syncthreads();
    if (tid < 64) {
        float m = fmaxf(fmaxf(redm[tid], redm[tid + 64]),
                        fmaxf(redm[tid + 128], redm[tid + 192]));
#pragma unroll
        for (int off = 32; off >= 1; off >>= 1) m = fmaxf(m, __shfl_xor(m, off, 64));
        if (tid == 0) e1maxS = m;
    }
    __syncthreads();
    const float e1max = e1maxS;

    float ee2[2], mm[2];
    const float* e2g = E2 + (size_t)bh * 512 + qq * 128 + w * 32;
#pragma unroll
    for (int mt = 0; mt < 2; ++mt) {
        float v = e2g[mt * 16 + r];
        ee2[mt] = v;
        float s = e1max + v;
        mm[mt] = fmaxf(s, ALPHA * s);
    }

    f32x4 acc[2][4];
#pragma unroll
    for (int mt = 0; mt < 2; ++mt)
#pragma unroll
        for (int nt = 0; nt < 4; ++nt) {
            acc[mt][nt][0] = 0.f; acc[mt][nt][1] = 0.f;
            acc[mt][nt][2] = 0.f; acc[mt][nt][3] = 0.f;
        }
    float zac[2] = {0.f, 0.f};

    const int d_s = tid >> 2, kq = tid & 3;
    const __bf16* hsrc = HT + (size_t)(bh * 64 + d_s) * 512 + kq * 8;
    const int lwo = d_s * 64 + ((kq * 16) ^ ((d_s & 3) << 4));
    char* cur = Hc0;
    char* nxt = Hc1;
    *(bf16x8*)(cur + lwo) = *(const bf16x8*)hsrc;
    __syncthreads();

    for (int c = 0; c < 16; ++c) {
        bf16x8 stg;
        if (c < 15) stg = *(const bf16x8*)(hsrc + (c + 1) * 32);  // issue early

        const float* ep = e1s + c * 32 + g * 8;
        float4 ea = *(const float4*)(ep);
        float4 eb = *(const float4*)(ep + 4);
        float e1c[8] = {ea.x, ea.y, ea.z, ea.w, eb.x, eb.y, eb.z, eb.w};

        bf16x8 bfr[4];
#pragma unroll
        for (int nt = 0; nt < 4; ++nt) {
            int d = nt * 16 + r;
            bfr[nt] = *(const bf16x8*)(cur + d * 64 + ((g * 16) ^ ((d & 3) << 4)));
        }
#pragma unroll
        for (int mt = 0; mt < 2; ++mt) {
            bf16x8 af;
            float zp = 0.f;
#pragma unroll
            for (int q = 0; q < 8; ++q) {
                float s = e1c[q] + ee2[mt];
                s = fmaxf(s, ALPHA * s);
                float p = __expf(s - mm[mt]);
                zp += p;
                af[q] = (__bf16)p;
            }
            zac[mt] += zp;
#pragma unroll
            for (int nt = 0; nt < 4; ++nt)
                acc[mt][nt] =
                    __builtin_amdgcn_mfma_f32_16x16x32_bf16(af, bfr[nt], acc[mt][nt], 0, 0, 0);
        }

        if (c < 15) *(bf16x8*)(nxt + lwo) = stg;  // write to idle buffer
        __syncthreads();                          // one barrier per chunk
        char* t = cur; cur = nxt; nxt = t;
    }

#pragma unroll
    for (int mt = 0; mt < 2; ++mt) {
        float z = zac[mt];
        z += __shfl_xor(z, 16, 64);
        z += __shfl_xor(z, 32, 64);
        if (g == 0) zrow[w][mt * 16 + r] = 1.f / z;
    }

    __bf16* ob = OL + ((size_t)b * 512 + qq * 128 + w * 32) * 512 + h * 64;
#pragma unroll
    for (int mt = 0; mt < 2; ++mt) {
#pragma unroll
        for (int reg = 0; reg < 4; ++reg) {
            int row = mt * 16 + g * 4 + reg;
            float zi = zrow[w][row];
#pragma unroll
            for (int nt = 0; nt < 4; ++nt) {
                float v = acc[mt][nt][reg] * zi;
                v = fmaxf(v, ACVT * v);  // leaky 0.01 fused
                ob[(size_t)row * 512 + nt * 16 + r] = (__bf16)v;
            }
        }
    }
}

// ============================================================================
// GEMM2: H2[m][c] = sum_k OL[m][k] * Wo[c][k] (bf16 out), fused f1/f2.
// BM=32, BN=128, KC=64, grid 512. Ping-pong double-buffered staging:
// one barrier per K-chunk (8 vs 16), loads issued before compute.
// ============================================================================
__global__ __launch_bounds__(256) void gemm2_f(
    const __bf16* __restrict__ OL, const float* __restrict__ Wo,
    __bf16* __restrict__ H2,
    const float* __restrict__ a1o, const float* __restrict__ a2o,
    float* __restrict__ F1, float* __restrict__ F2) {
    __shared__ char As0[4096], As1[4096];
    __shared__ char Bs0[16384], Bs1[16384];
    __shared__ float fred[2][32][2];
    const int tid = threadIdx.x;
    const int w = tid >> 6, lane = tid & 63;
    const int wm = w >> 1, wn = w & 1;
    const int r = lane & 15, g = lane >> 4;
    const int m0 = blockIdx.x * 32;

    f32x4 acc[4];
#pragma unroll
    for (int nt = 0; nt < 4; ++nt) {
        acc[nt][0] = 0.f; acc[nt][1] = 0.f; acc[nt][2] = 0.f; acc[nt][3] = 0.f;
    }

    const int sra = tid >> 3;        // 0..31
    const int c8 = (tid & 7) * 8;
    const int aoff = sra * 128 + ((c8 * 2) ^ ((sra & 7) << 4));

    // ---- prologue: stage chunk 0 ----
    {
        bf16x8 va = *(const bf16x8*)(OL + (size_t)(m0 + sra) * 512 + c8);
        *(bf16x8*)(As0 + aoff) = va;
#pragma unroll
        for (int i = 0; i < 4; ++i) {
            int row = sra + i * 32;
            bf16x8 vb = cvt8(Wo + (size_t)row * 512 + c8);
            *(bf16x8*)(Bs0 + row * 128 + ((c8 * 2) ^ ((row & 7) << 4))) = vb;
        }
    }
    __syncthreads();
    char* Ac = As0; char* An = As1;
    char* Bc = Bs0; char* Bn = Bs1;

    for (int c = 0; c < 8; ++c) {
        bf16x8 nva, nvb0, nvb1, nvb2, nvb3;
        if (c < 7) {   // issue next-chunk loads before compute
            int k0n = (c + 1) * 64;
            nva = *(const bf16x8*)(OL + (size_t)(m0 + sra) * 512 + k0n + c8);
            nvb0 = cvt8(Wo + (size_t)(sra) * 512 + k0n + c8);
            nvb1 = cvt8(Wo + (size_t)(sra + 32) * 512 + k0n + c8);
            nvb2 = cvt8(Wo + (size_t)(sra + 64) * 512 + k0n + c8);
            nvb3 = cvt8(Wo + (size_t)(sra + 96) * 512 + k0n + c8);
        }
#pragma unroll
        for (int kk = 0; kk < 64; kk += 32) {
            int arow = wm * 16 + r;
            bf16x8 af = *(const bf16x8*)(Ac + arow * 128 +
                                         (((kk + g * 8) * 2) ^ ((arow & 7) << 4)));
            bf16x8 bfv[4];
#pragma unroll
            for (int nt = 0; nt < 4; ++nt) {
                int row = wn * 64 + nt * 16 + r;
                bfv[nt] = *(const bf16x8*)(Bc + row * 128 +
                                           (((kk + g * 8) * 2) ^ ((row & 7) << 4)));
            }
#pragma unroll
            for (int nt = 0; nt < 4; ++nt)
                acc[nt] = __builtin_amdgcn_mfma_f32_16x16x32_bf16(af, bfv[nt], acc[nt], 0, 0, 0);
        }
        if (c < 7) {   // write to idle buffers
            *(bf16x8*)(An + aoff) = nva;
            *(bf16x8*)(Bn + sra * 128 + ((c8 * 2) ^ ((sra & 7) << 4))) = nvb0;
            *(bf16x8*)(Bn + (sra + 32) * 128 + ((c8 * 2) ^ (((sra + 32) & 7) << 4))) = nvb1;
            *(bf16x8*)(Bn + (sra + 64) * 128 + ((c8 * 2) ^ (((sra + 64) & 7) << 4))) = nvb2;
            *(bf16x8*)(Bn + (sra + 96) * 128 + ((c8 * 2) ^ (((sra + 96) & 7) << 4))) = nvb3;
        }
        __syncthreads();
        char* t = Ac; Ac = An; An = t;
        t = Bc; Bc = Bn; Bn = t;
    }

#pragma unroll
    for (int reg = 0; reg < 4; ++reg) {
        int row = m0 + wm * 16 + g * 4 + reg;
#pragma unroll
        for (int nt = 0; nt < 4; ++nt)
            H2[(size_t)row * 128 + wn * 64 + nt * 16 + r] = (__bf16)acc[nt][reg];
    }
    float w1[4], w2[4];
#pragma unroll
    for (int nt = 0; nt < 4; ++nt) {
        w1[nt] = a1o[wn * 64 + nt * 16 + r];
        w2[nt] = a2o[wn * 64 + nt * 16 + r];
    }
#pragma unroll
    for (int reg = 0; reg < 4; ++reg) {
        float s1 = 0.f, s2 = 0.f;
#pragma unroll
        for (int nt = 0; nt < 4; ++nt) {
            s1 += acc[nt][reg] * w1[nt];
            s2 += acc[nt][reg] * w2[nt];
        }
#pragma unroll
        for (int off = 1; off <= 8; off <<= 1) {
            s1 += __shfl_xor(s1, off, 64);
            s2 += __shfl_xor(s2, off, 64);
        }
        if (r == 0) {
            int lr = wm * 16 + g * 4 + reg;
            fred[wn][lr][0] = s1;
            fred[wn][lr][1] = s2;
        }
    }
    __syncthreads();
    if (tid < 32) {
        int m = m0 + tid;
        int b = m >> 9, n = m & 511;
        F1[(size_t)b * 512 + n] = fred[0][tid][0] + fred[1][tid][0];
        F2[(size_t)b * 512 + n] = fred[0][tid][1] + fred[1][tid][1];
    }
}

// ============================================================================
// zw: per (b, jc): partial w[k] = sum_{j in chunk} softmax_k(leaky(f1+f2))[j,k]
// ============================================================================
__global__ __launch_bounds__(256) void zw_k(const float* __restrict__ F1,
                                            const float* __restrict__ F2,
                                            float* __restrict__ WP) {
    __shared__ float f1s[512];
    __shared__ float wpart[4][512];
    __shared__ float redm[256];
    const int b = blockIdx.x >> 4, jc = blockIdx.x & 15;
    const int tid = threadIdx.x;
    const int w = tid >> 6, lane = tid & 63;

    f1s[tid] = F1[(size_t)b * 512 + tid];
    f1s[tid + 256] = F1[(size_t)b * 512 + tid + 256];
#pragma unroll
    for (int i = 0; i < 8; ++i) wpart[w][lane + 64 * i] = 0.f;
    __syncthreads();
    redm[tid] = fmaxf(f1s[tid], f1s[tid + 256]);
    __syncthreads();
    if (tid < 64) {
        float m = fmaxf(fmaxf(redm[tid], redm[tid + 64]), fmaxf(redm[tid + 128], redm[tid + 192]));
#pragma unroll
        for (int off = 32; off >= 1; off >>= 1) m = fmaxf(m, __shfl_xor(m, off, 64));
        if (tid == 0) redm[0] = m;
    }
    __syncthreads();
    const float f1m = redm[0];

    for (int jj = 0; jj < 8; ++jj) {
        int j = jc * 32 + w * 8 + jj;
        float f2j = F2[(size_t)b * 512 + j];
        float sj = f1m + f2j;
        float mj = fmaxf(sj, ALPHA * sj);
        float pv[8];
        float z = 0.f;
#pragma unroll
        for (int i = 0; i < 8; ++i) {
            float s = f1s[lane + 64 * i] + f2j;
            s = fmaxf(s, ALPHA * s);
            float p = __expf(s - mj);
            pv[i] = p;
            z += p;
        }
#pragma unroll
        for (int off = 32; off >= 1; off >>= 1) z += __shfl_xor(z, off, 64);
        float inv = 1.f / z;
#pragma unroll
        for (int i = 0; i < 8; ++i) wpart[w][lane + 64 * i] += pv[i] * inv;
    }
    __syncthreads();
    for (int i = tid; i < 512; i += 256)
        WP[(size_t)(b * 16 + jc) * 512 + i] =
            wpart[0][i] + wpart[1][i] + wpart[2][i] + wpart[3][i];
}

// ============================================================================
// finalv: per b: w = sum WP; v = (w/512) . H2; out = normalize(v @ Wl^T + bl)
// ============================================================================
__global__ __launch_bounds__(512) void finalv_k(const float* __restrict__ WP,
                                                const __bf16* __restrict__ H2,
                                                const float* __restrict__ Wl,
                                                const float* __restrict__ bl,
                                                float* __restrict__ out) {
    __shared__ float wsL[512];
    __shared__ float part[4][128];
    __shared__ float vs[128];
    __shared__ float fo_s[128];
    __shared__ float r0;
    const int b = blockIdx.x, tid = threadIdx.x;
    {
        float s = 0.f;
#pragma unroll
        for (int jc = 0; jc < 16; ++jc) s += WP[(size_t)(b * 16 + jc) * 512 + tid];
        wsL[tid] = s;
    }
    __syncthreads();
    {
        const int q = tid >> 7, d = tid & 127;
        const __bf16* h2p = H2 + ((size_t)b * 512 + q * 128) * 128 + d;
        float acc = 0.f;
#pragma unroll 8
        for (int i = 0; i < 128; ++i) acc += wsL[q * 128 + i] * (float)h2p[(size_t)i * 128];
        part[q][d] = acc;
    }
    __syncthreads();
    if (tid < 128)
        vs[tid] = (part[0][tid] + part[1][tid] + part[2][tid] + part[3][tid]) * (1.f / 512.f);
    __syncthreads();
    if (tid < 128) {
        float fo = bl[tid];
        const float* wl = Wl + (size_t)tid * 128;
#pragma unroll 4
        for (int d = 0; d < 128; d += 4)
            fo += vs[d] * wl[d] + vs[d + 1] * wl[d + 1] + vs[d + 2] * wl[d + 2] +
                  vs[d + 3] * wl[d + 3];
        fo_s[tid] = fo;
    }
    __syncthreads();
    if (tid < 64) {
        float s = fo_s[tid] * fo_s[tid] + fo_s[tid + 64] * fo_s[tid + 64];
#pragma unroll
        for (int off = 32; off >= 1; off >>= 1) s += __shfl_xor(s, off, 64);
        if (tid == 0) r0 = s;
    }
    __syncthreads();
    float inv = 1.f / fmaxf(sqrtf(r0), 1e-12f);
    if (tid < 128) out[(size_t)b * 128 + tid] = fo_s[tid] * inv;
}

extern "C" void kernel_launch(void* const* d_in, const int* in_sizes, int n_in,
                              void* d_out, int out_size, void* d_ws, size_t ws_size,
                              hipStream_t stream) {
    const float* X = (const float*)d_in[0];
    const float* Wt = (const float*)d_in[1];
    const float* a1 = (const float*)d_in[2];
    const float* a2 = (const float*)d_in[3];
    const float* Wo = (const float*)d_in[4];
    const float* a1o = (const float*)d_in[5];
    const float* a2o = (const float*)d_in[6];
    const float* Wl = (const float*)d_in[7];
    const float* bl = (const float*)d_in[8];
    float* out = (float*)d_out;

    char* p = (char*)d_ws;
    __bf16* HT = (__bf16*)p;  p += (size_t)8388608 * 2;   // 16 MB
    __bf16* OL = (__bf16*)p;  p += (size_t)8388608 * 2;   // 16 MB
    float* E1 = (float*)p;    p += (size_t)131072 * 4;
    float* E2 = (float*)p;    p += (size_t)131072 * 4;
    __bf16* H2 = (__bf16*)p;  p += (size_t)2097152 * 2;   // 4 MB
    float* F1 = (float*)p;    p += (size_t)16384 * 4;
    float* F2 = (float*)p;    p += (size_t)16384 * 4;
    float* WP = (float*)p;    p += (size_t)262144 * 4;    // 1 MB

    gemm1_f<<<512, 256, 0, stream>>>(X, Wt, HT, a1, a2, E1, E2);
    attn_s<<<1024, 256, 0, stream>>>(HT, E1, E2, OL);
    gemm2_f<<<512, 256, 0, stream>>>(OL, Wo, H2, a1o, a2o, F1, F2);
    zw_k<<<512, 256, 0, stream>>>(F1, F2, WP);
    finalv_k<<<32, 512, 0, stream>>>(WP, H2, Wl, bl, out);
}